// Round 1
// baseline (235.213 us; speedup 1.0000x reference)
//
#include <hip/hip_runtime.h>

// OHEM loss, specialized for NUM_CLASSES == 1:
//   ce = logsumexp(cls_preds, axis=2) - cls_preds[...,0] == 0 exactly,
//   so cls_loss == 0 and hard-negative mining is dead code.
//   out = 0.2 * sum_{pos} smooth_l1(loc_preds - loc_targets) / num_pos
// Pure memory-bound masked reduction over 217.6 MB.

constexpr int NBLK = 2048;
constexpr int BLK  = 256;

__device__ __forceinline__ float sl1(float d) {
    float ax = fabsf(d);
    return (ax < 1.0f) ? 0.5f * d * d : ax - 0.5f;
}

__global__ __launch_bounds__(BLK) void ohem_partial(
        const float* __restrict__ loc_p,
        const float* __restrict__ loc_t,
        const int*   __restrict__ cls_t,
        double* __restrict__ part_sum,
        int*    __restrict__ part_cnt,
        int n_anchor)
{
    double acc = 0.0;
    int cnt = 0;
    const int stride = gridDim.x * blockDim.x;
    for (int i = blockIdx.x * blockDim.x + threadIdx.x; i < n_anchor; i += stride) {
        const int t = cls_t[i];
        const float4* p = reinterpret_cast<const float4*>(loc_p) + (size_t)i * 2;
        const float4* q = reinterpret_cast<const float4*>(loc_t) + (size_t)i * 2;
        // Unconditional loads: fully coalesced, keeps the fetch stream regular.
        float4 p0 = p[0], p1 = p[1];
        float4 q0 = q[0], q1 = q[1];
        if (t > 0) {
            float s = sl1(p0.x - q0.x) + sl1(p0.y - q0.y)
                    + sl1(p0.z - q0.z) + sl1(p0.w - q0.w)
                    + sl1(p1.x - q1.x) + sl1(p1.y - q1.y)
                    + sl1(p1.z - q1.z) + sl1(p1.w - q1.w);
            acc += (double)s;
            cnt += 1;
        }
    }
    // wave-64 butterfly-style reduce (lane 0 ends with the wave total)
    #pragma unroll
    for (int off = 32; off > 0; off >>= 1) {
        acc += __shfl_down(acc, off, 64);
        cnt += __shfl_down(cnt, off, 64);
    }
    __shared__ double ssum[BLK / 64];
    __shared__ int    scnt[BLK / 64];
    const int lane = threadIdx.x & 63;
    const int wid  = threadIdx.x >> 6;
    if (lane == 0) { ssum[wid] = acc; scnt[wid] = cnt; }
    __syncthreads();
    if (threadIdx.x == 0) {
        double a = 0.0; int c = 0;
        #pragma unroll
        for (int w = 0; w < BLK / 64; ++w) { a += ssum[w]; c += scnt[w]; }
        part_sum[blockIdx.x] = a;
        part_cnt[blockIdx.x] = c;
    }
}

__global__ __launch_bounds__(BLK) void ohem_final(
        const double* __restrict__ part_sum,
        const int*    __restrict__ part_cnt,
        float* __restrict__ out, int nblk)
{
    double acc = 0.0;
    long long cnt = 0;
    for (int i = threadIdx.x; i < nblk; i += BLK) {
        acc += part_sum[i];
        cnt += part_cnt[i];
    }
    #pragma unroll
    for (int off = 32; off > 0; off >>= 1) {
        acc += __shfl_down(acc, off, 64);
        cnt += __shfl_down(cnt, off, 64);
    }
    __shared__ double    ssum[BLK / 64];
    __shared__ long long scnt[BLK / 64];
    const int lane = threadIdx.x & 63;
    const int wid  = threadIdx.x >> 6;
    if (lane == 0) { ssum[wid] = acc; scnt[wid] = cnt; }
    __syncthreads();
    if (threadIdx.x == 0) {
        double a = 0.0; long long c = 0;
        #pragma unroll
        for (int w = 0; w < BLK / 64; ++w) { a += ssum[w]; c += scnt[w]; }
        out[0] = (float)(0.2 * a / (double)c);
    }
}

extern "C" void kernel_launch(void* const* d_in, const int* in_sizes, int n_in,
                              void* d_out, int out_size, void* d_ws, size_t ws_size,
                              hipStream_t stream) {
    const float* loc_p = (const float*)d_in[0];   // [B, A, 8] f32
    const float* loc_t = (const float*)d_in[1];   // [B, A, 8] f32
    // d_in[2] (cls_preds) is provably unused: ce == 0 when C == 1.
    const int*   cls_t = (const int*)d_in[3];     // [B, A] i32
    const int n_anchor = in_sizes[3];             // B * A

    double* part_sum = (double*)d_ws;
    int*    part_cnt = (int*)((char*)d_ws + NBLK * sizeof(double));

    ohem_partial<<<NBLK, BLK, 0, stream>>>(loc_p, loc_t, cls_t,
                                           part_sum, part_cnt, n_anchor);
    ohem_final<<<1, BLK, 0, stream>>>(part_sum, part_cnt, (float*)d_out, NBLK);
}